// Round 1
// baseline (111.044 us; speedup 1.0000x reference)
//
#include <hip/hip_runtime.h>

// NormalizePixelPts: out[f][d] = in[f][d] * scale(d)
// scale(d) in {1.0, 1/1280, 1/720} per the build_scale() index walk:
//   FEAT_DIM = 4178, layout:
//     d in [0, 570): two k-blocks of 285:
//       r = d % 285
//       r == 0            -> 1.0        (RH activation)
//       r in [1, 80]      -> pair (1/W, 1/H), parity (r-1)&1   (obj-RH dists)
//       r == 81           -> 1.0        (LH activation)
//       r in [82, 163]    -> pair (1/W, 1/H), parity (r-82)&1  (obj-LH dists + RH-LH dist)
//       r in [164, 284]   -> 1.0        (intersection + per-obj conf/intersections)
//     d in [570, 4178): joint offsets, pair (1/W, 1/H), parity (d-570)&1
//       (570..657 hand joints, 658..4177 object joints; parity continuous
//        because 658-570 = 88 is even and both runs start x-first)

#define FEAT_DIM 4178
#define SPLIT    570
#define KBLK     285

__device__ __forceinline__ float scale_for(int d) {
    const float inv_w = 1.0f / 1280.0f;
    const float inv_h = 1.0f / 720.0f;
    if (d < SPLIT) {
        int r = d % KBLK;
        if (r == 0 || r == 81 || r >= 164) return 1.0f;
        if (r <= 80) return ((r - 1) & 1) ? inv_h : inv_w;
        return ((r - 82) & 1) ? inv_h : inv_w;  // covers 82..163 (incl. RH-LH at 162/163)
    }
    return ((d - 570) & 1) ? inv_h : inv_w;
}

__global__ void __launch_bounds__(256)
normalize_pixel_pts_kernel(const float4* __restrict__ in, float4* __restrict__ out, int n4) {
    int idx = blockIdx.x * blockDim.x + threadIdx.x;
    int stride = gridDim.x * blockDim.x;
    for (int i = idx; i < n4; i += stride) {
        float4 v = in[i];
        // column index of the first element of this float4
        int d0 = (i * 4) % FEAT_DIM;   // i*4 < 2^31, safe in int32
        int d1 = d0 + 1; if (d1 >= FEAT_DIM) d1 -= FEAT_DIM;
        int d2 = d1 + 1; if (d2 >= FEAT_DIM) d2 -= FEAT_DIM;
        int d3 = d2 + 1; if (d3 >= FEAT_DIM) d3 -= FEAT_DIM;
        v.x *= scale_for(d0);
        v.y *= scale_for(d1);
        v.z *= scale_for(d2);
        v.w *= scale_for(d3);
        out[i] = v;
    }
}

extern "C" void kernel_launch(void* const* d_in, const int* in_sizes, int n_in,
                              void* d_out, int out_size, void* d_ws, size_t ws_size,
                              hipStream_t stream) {
    const float4* in = (const float4*)d_in[0];
    float4* out = (float4*)d_out;
    int n4 = out_size / 4;  // 68,452,352 / 4 = 17,113,088 (exactly divisible)

    const int block = 256;
    int blocks_needed = (n4 + block - 1) / block;
    int grid = blocks_needed < 2048 ? blocks_needed : 2048;  // grid-stride beyond

    normalize_pixel_pts_kernel<<<grid, block, 0, stream>>>(in, out, n4);
}

// Round 2
// 100.991 us; speedup vs baseline: 1.0996x; 1.0996x over previous
//
#include <hip/hip_runtime.h>

// NormalizePixelPts: out[f][d] = in[f][d] * scale(d), scale in {1, 1/1280, 1/720}.
// Flat float4 view: float4 i covers columns (4i..4i+3) mod 4178.
// Since gcd(4,4178)=2, the scale-quad pattern has period 2089 in float4 index.
// We build a 2089-entry float4 LDS table indexed by j = i mod 2089
// (consecutive lanes -> consecutive entries -> conflict-free ds_read_b128),
// and advance j incrementally in the grid-stride loop (no per-iter modulo).

#define FEAT_DIM 4178
#define SPLIT    570
#define KBLK     285
#define HALF     2089   // float4-phase period

__device__ __forceinline__ float scale_for(int d) {
    const float inv_w = 1.0f / 1280.0f;
    const float inv_h = 1.0f / 720.0f;
    if (d >= FEAT_DIM) d -= FEAT_DIM;   // callers pass d < 2*FEAT_DIM
    if (d < SPLIT) {
        int r = d % KBLK;
        if (r == 0 || r == 81 || r >= 164) return 1.0f;
        if (r <= 80) return ((r - 1) & 1) ? inv_h : inv_w;
        return ((r - 82) & 1) ? inv_h : inv_w;  // 82..163 incl. RH-LH pair
    }
    return ((d - 570) & 1) ? inv_h : inv_w;
}

__global__ void __launch_bounds__(256)
normalize_pixel_pts_kernel(const float4* __restrict__ in, float4* __restrict__ out, int n4) {
    __shared__ float4 tbl[HALF];   // 33,424 B -> 4 blocks/CU, 16 waves/CU

    // Build the per-phase scale quads once per block (~9 iters/thread).
    for (int t = threadIdx.x; t < HALF; t += 256) {
        int d0 = 4 * t;                        // <= 8352 < 2*FEAT_DIM
        if (d0 >= FEAT_DIM) d0 -= FEAT_DIM;    // d0 even, <= 4176
        float4 s;
        s.x = scale_for(d0);
        s.y = scale_for(d0 + 1);
        s.z = scale_for(d0 + 2);               // may wrap (handled in scale_for)
        s.w = scale_for(d0 + 3);
        tbl[t] = s;
    }
    __syncthreads();

    int idx = blockIdx.x * blockDim.x + threadIdx.x;
    int stride = gridDim.x * blockDim.x;
    int j = idx % HALF;            // phase of float4 idx; 4i mod 4178 == 4(i mod 2089) mod 4178
    int jstep = stride % HALF;
    for (int i = idx; i < n4; i += stride) {
        float4 v = in[i];
        float4 s = tbl[j];
        v.x *= s.x; v.y *= s.y; v.z *= s.z; v.w *= s.w;
        out[i] = v;
        j += jstep;
        if (j >= HALF) j -= HALF;
    }
}

extern "C" void kernel_launch(void* const* d_in, const int* in_sizes, int n_in,
                              void* d_out, int out_size, void* d_ws, size_t ws_size,
                              hipStream_t stream) {
    const float4* in = (const float4*)d_in[0];
    float4* out = (float4*)d_out;
    int n4 = out_size / 4;         // 68,452,352 / 4 = 17,113,088 exactly

    const int block = 256;
    const int grid = 1024;         // 4 blocks/CU (LDS-limited), table built once each
    normalize_pixel_pts_kernel<<<grid, block, 0, stream>>>(in, out, n4);
}